// Round 7
// baseline (381.541 us; speedup 1.0000x reference)
//
#include <hip/hip_runtime.h>
#include <hip/hip_bf16.h>
#include <hip/hip_cooperative_groups.h>

namespace cg = cooperative_groups;

// ---------------------------------------------------------------------------
// Primary: ONE cooperative kernel, 256 blocks x 512 thr (1 block/CU — always
// launchable), 6 phases with __threadfence()+grid.sync() between:
//  P0: stage dep/rgb tile (g*2) to LDS + weight pack (blocks<6)
//  P1: 2x { conv+BN+ReLU -> proj pr_e/pd -> rgbd partial } (tiles g*2, g*2+1)
//  P2: Z[b][j] = sum_i exp2(e2)  (block = one 64-wide j-tile, full 4096 i)
//  P3: s_i over full 4096 j + gap partial (block = one 64-wide i-tile)
//  P4: reduce 512+256 partial rows -> 32
//  P5: gap -> MLP -> sigmoid -> out (block 0)
// Fallback (if hipLaunchCooperativeKernel errors): proven R5 5-kernel path.
//   e2 = <pr,pd>*0.125*log2e: pr_e stored pre-scaled; gap un-scales by K_EINV.
// ---------------------------------------------------------------------------

typedef __bf16 bf16;
typedef __bf16 bf16x4 __attribute__((ext_vector_type(4)));
typedef __bf16 bf16x8 __attribute__((ext_vector_type(8)));
typedef float  f32x4  __attribute__((ext_vector_type(4)));
typedef float  float4v __attribute__((ext_vector_type(4)));

#define MFMA_BF16(a, b, c) __builtin_amdgcn_mfma_f32_16x16x32_bf16((a), (b), (c), 0, 0, 0)

#if defined(__has_builtin)
# if __has_builtin(__builtin_amdgcn_exp2f)
#  define EXP2(x) __builtin_amdgcn_exp2f(x)
# else
#  define EXP2(x) exp2f(x)
# endif
#else
# define EXP2(x) exp2f(x)
#endif

#define K_E 0.18033688f      // 0.125 * log2(e)
#define K_EINV 5.5451774f    // 1 / K_E

__device__ __forceinline__ int swz128(int row, int colByte) {
    return row * 128 + (colByte ^ ((row & 7) << 4));
}
__device__ __forceinline__ int swz512(int row, int colByte) {
    return row * 512 + (colByte ^ ((row & 15) << 4));
}

// LDS layout (P1); P2+ alias from offset 0
#define O_LDSC 0            // [32][512B] dep tile bf16 [p][c256]
#define O_LDSR 16384        // [32][128B] rgb tile
#define O_LDSD 20480        // [32][128B] depf tile
#define O_S1   24576
#define O_B1   24832
#define O_RED  25088        // 8*64*4
#define SMEM_BYTES 27136

__device__ __forceinline__ void stage_tile(
    const float* __restrict__ depb, const float* __restrict__ rgbb,
    int p0, int tid, unsigned char* ldsC, unsigned char* ldsR)
{
    const int c0 = tid >> 3, seg = tid & 7;
    #pragma unroll
    for (int r = 0; r < 4; ++r) {
        const int c = r * 64 + c0;
        float4v v = *(const float4v*)(depb + (size_t)c * 4096 + p0 + seg * 4);
        #pragma unroll
        for (int k = 0; k < 4; ++k)
            *(bf16*)(ldsC + swz512(seg * 4 + k, c * 2)) = (bf16)v[k];
    }
    float4v v = *(const float4v*)(rgbb + (size_t)c0 * 4096 + p0 + seg * 4);
    #pragma unroll
    for (int k = 0; k < 4; ++k)
        *(bf16*)(ldsR + swz128(seg * 4 + k, c0 * 2)) = (bf16)v[k];
}

__global__ __launch_bounds__(512, 2) void k_fused(
    const float* __restrict__ rgb, const float* __restrict__ dep,
    const float* __restrict__ conv_w,
    const float* __restrict__ bn1_g, const float* __restrict__ bn1_b,
    const float* __restrict__ bn1_m, const float* __restrict__ bn1_v,
    const float* __restrict__ rgb_w, const float* __restrict__ dep_w,
    const float* __restrict__ mlp1_w,
    const float* __restrict__ bn2_g, const float* __restrict__ bn2_b,
    const float* __restrict__ bn2_m, const float* __restrict__ bn2_v,
    const float* __restrict__ mlp2_w,
    const float* __restrict__ bn3_g, const float* __restrict__ bn3_b,
    const float* __restrict__ bn3_m, const float* __restrict__ bn3_v,
    bf16* __restrict__ wC, bf16* __restrict__ wR, bf16* __restrict__ wD,
    bf16* __restrict__ pr_e, bf16* __restrict__ pd_,
    float* __restrict__ Z, float* __restrict__ rgbdPart,
    float* __restrict__ gapPart, float* __restrict__ red2,
    float* __restrict__ outp)
{
    cg::grid_group grid = cg::this_grid();
    const int bid = blockIdx.x, tid = threadIdx.x;
    const int xcd = bid & 7, b = xcd >> 1;
    const int g = ((bid >> 3) << 1) | (xcd & 1);      // 0..63 within batch
    const int lane = tid & 63, w = tid >> 6;
    const int l15 = lane & 15, lg = lane >> 4;

    __shared__ __align__(16) unsigned char smem[SMEM_BYTES];
    unsigned char* ldsC = smem + O_LDSC;
    unsigned char* ldsR = smem + O_LDSR;
    unsigned char* ldsD = smem + O_LDSD;
    float* s1 = (float*)(smem + O_S1);
    float* b1 = (float*)(smem + O_B1);
    float* red = (float*)(smem + O_RED);   // [8][64]

    const float* depb = dep + (size_t)b * 256 * 4096;
    const float* rgbb = rgb + (size_t)b * 64 * 4096;

    // ================= P0: stage tile g*2 + weight pack ====================
    stage_tile(depb, rgbb, g * 2 * 32, tid, ldsC, ldsR);
    if (tid < 64) {
        float sc = bn1_g[tid] * rsqrtf(bn1_v[tid] + 1e-5f);
        s1[tid] = sc;
        b1[tid] = bn1_b[tid] - bn1_m[tid] * sc;
    }
    if (bid < 6) {   // pack 3072 octets
        const int gid = bid * 512 + tid;
        bf16x8 v;
        if (gid < 2048) {
            const int t = gid >> 9, kk = (gid >> 6) & 7, ln = gid & 63;
            const float* src = conv_w + (size_t)(t * 16 + (ln & 15)) * 256
                                      + kk * 32 + (ln >> 4) * 8;
            #pragma unroll
            for (int j = 0; j < 8; ++j) v[j] = (bf16)src[j];
            *(bf16x8*)(wC + (size_t)gid * 8) = v;
        } else if (gid < 2560) {
            const int gg = gid - 2048;
            const int t = gg >> 7, kk = (gg >> 6) & 1, ln = gg & 63;
            const float* src = rgb_w + (size_t)(t * 16 + (ln & 15)) * 64
                                     + kk * 32 + (ln >> 4) * 8;
            #pragma unroll
            for (int j = 0; j < 8; ++j) v[j] = (bf16)src[j];
            *(bf16x8*)(wR + (size_t)gg * 8) = v;
        } else {
            const int gg = gid - 2560;
            const int t = gg >> 7, kk = (gg >> 6) & 1, ln = gg & 63;
            const float* src = dep_w + (size_t)(t * 16 + (ln & 15)) * 64
                                     + kk * 32 + (ln >> 4) * 8;
            #pragma unroll
            for (int j = 0; j < 8; ++j) v[j] = (bf16)src[j];
            *(bf16x8*)(wD + (size_t)gg * 8) = v;
        }
    }
    __threadfence();
    grid.sync();

    // ================= P1: conv + proj for tiles g*2, g*2+1 ================
    {
        const int ot4 = w & 3, ot = ot4 * 16, ph = w >> 2;
        const int prow = ph * 16 + l15;
        bf16x8 aW[8];
        #pragma unroll
        for (int kk = 0; kk < 8; ++kk)
            aW[kk] = *(const bf16x8*)(wC + ((size_t)(ot4 * 8 + kk) * 64 + lane) * 8);
        bf16x8 aR[2], aD[2];
        #pragma unroll
        for (int kk = 0; kk < 2; ++kk) {
            aR[kk] = *(const bf16x8*)(wR + ((size_t)(ot4 * 2 + kk) * 64 + lane) * 8);
            aD[kk] = *(const bf16x8*)(wD + ((size_t)(ot4 * 2 + kk) * 64 + lane) * 8);
        }
        for (int half = 0; half < 2; ++half) {
            const int tile = g * 2 + half;
            const int p0h = tile * 32;
            if (half) {
                __syncthreads();
                stage_tile(depb, rgbb, p0h, tid, ldsC, ldsR);
                __syncthreads();
            }
            f32x4 acc = {0.f, 0.f, 0.f, 0.f};
            #pragma unroll
            for (int kk = 0; kk < 8; ++kk) {
                bf16x8 bF = *(const bf16x8*)(ldsC + swz512(prow, (kk * 32 + lg * 8) * 2));
                acc = MFMA_BF16(aW[kk], bF, acc);
            }
            {
                const int o0 = ot + lg * 4;
                bf16x4 v4;
                #pragma unroll
                for (int r = 0; r < 4; ++r) {
                    float x = acc[r] * s1[o0 + r] + b1[o0 + r];
                    v4[r] = (bf16)(x > 0.f ? x : 0.f);
                }
                *(bf16x4*)(ldsD + swz128(prow, o0 * 2)) = v4;
            }
            __syncthreads();
            f32x4 accR = {0.f, 0.f, 0.f, 0.f}, accD = {0.f, 0.f, 0.f, 0.f};
            #pragma unroll
            for (int kk = 0; kk < 2; ++kk) {
                const int cb = (kk * 32 + lg * 8) * 2;
                bf16x8 bR = *(const bf16x8*)(ldsR + swz128(prow, cb));
                bf16x8 bD = *(const bf16x8*)(ldsD + swz128(prow, cb));
                accR = MFMA_BF16(aR[kk], bR, accR);
                accD = MFMA_BF16(aD[kk], bD, accD);
            }
            bf16x4 vR, vD;
            #pragma unroll
            for (int r = 0; r < 4; ++r) {
                vR[r] = (bf16)(accR[r] * K_E);
                vD[r] = (bf16)accD[r];
            }
            const size_t ob = ((size_t)b * 4096 + p0h + prow) * 64 + ot + lg * 4;
            *(bf16x4*)(pr_e + ob) = vR;
            *(bf16x4*)(pd_ + ob) = vD;

            float sum = 0.f;
            #pragma unroll
            for (int q = 0; q < 4; ++q) {
                const int pp = w * 4 + q;
                sum += (float)*(const bf16*)(ldsR + swz128(pp, lane * 2))
                     + (float)*(const bf16*)(ldsD + swz128(pp, lane * 2));
            }
            red[w * 64 + lane] = sum;
            __syncthreads();
            if (tid < 64) {
                float s = 0.f;
                #pragma unroll
                for (int gg = 0; gg < 8; ++gg) s += red[gg * 64 + tid];
                rgbdPart[((size_t)b * 128 + tile) * 64 + tid] = s;
            }
        }
    }
    __threadfence();
    grid.sync();

    // ================= P2: Z[b][j] over full 4096 rows =====================
    {
        float* redz = (float*)smem;   // [8][64]
        const int j0 = g * 64;
        const bf16* prb = pr_e + (size_t)b * 4096 * 64;
        const bf16* pdb = pd_  + (size_t)b * 4096 * 64;
        const int cOff = lg * 8;

        bf16x8 bRes[4][2];
        #pragma unroll
        for (int jt = 0; jt < 4; ++jt) {
            const bf16* q = pdb + (size_t)(j0 + jt * 16 + l15) * 64 + cOff;
            bRes[jt][0] = *(const bf16x8*)q;
            bRes[jt][1] = *(const bf16x8*)(q + 32);
        }
        float zp[4] = {0.f, 0.f, 0.f, 0.f};
        const bf16* pa = prb + ((size_t)w * 16 + l15) * 64 + cOff;
        #pragma unroll 2
        for (int it = 0; it < 32; ++it) {
            bf16x8 a0 = *(const bf16x8*)pa;
            bf16x8 a1 = *(const bf16x8*)(pa + 32);
            pa += 128 * 64;
            #pragma unroll
            for (int jt = 0; jt < 4; ++jt) {
                f32x4 e = {0.f, 0.f, 0.f, 0.f};
                e = MFMA_BF16(a0, bRes[jt][0], e);
                e = MFMA_BF16(a1, bRes[jt][1], e);
                zp[jt] += (EXP2(e[0]) + EXP2(e[1])) + (EXP2(e[2]) + EXP2(e[3]));
            }
        }
        __syncthreads();   // LDS alias handoff
        #pragma unroll
        for (int jt = 0; jt < 4; ++jt) {
            float v = zp[jt];
            v += __shfl_xor(v, 16);
            v += __shfl_xor(v, 32);
            if (lane < 16) redz[w * 64 + jt * 16 + lane] = v;
        }
        __syncthreads();
        if (tid < 64) {
            float z = 0.f;
            #pragma unroll
            for (int gg = 0; gg < 8; ++gg) z += redz[gg * 64 + tid];
            Z[(size_t)b * 4096 + j0 + tid] = z;
        }
    }
    __threadfence();
    grid.sync();

    // ================= P3: s over full 4096 cols + gap partial =============
    {
        float* reds = (float*)smem;   // [8][64]
        const int i0 = g * 64;
        const bf16* prb = pr_e + (size_t)b * 4096 * 64;
        const bf16* pdb = pd_  + (size_t)b * 4096 * 64;
        const float* zb = Z + (size_t)b * 4096;
        const int cOff = lg * 8;

        bf16x8 aRes[4][2];
        #pragma unroll
        for (int rt = 0; rt < 4; ++rt) {
            const bf16* q = prb + (size_t)(i0 + rt * 16 + l15) * 64 + cOff;
            aRes[rt][0] = *(const bf16x8*)q;
            aRes[rt][1] = *(const bf16x8*)(q + 32);
        }
        float sacc[4][4] = {};
        const bf16*  pb = pdb + ((size_t)w * 16 + l15) * 64 + cOff;
        const float* pz = zb + w * 16 + l15;
        #pragma unroll 2
        for (int it = 0; it < 32; ++it) {
            bf16x8 b0 = *(const bf16x8*)pb;
            bf16x8 b1 = *(const bf16x8*)(pb + 32);
            pb += 128 * 64;
            float zv = pz[0];
            pz += 128;
            float zinv = __builtin_amdgcn_rcpf(zv);
            zinv = zinv * (2.0f - zv * zinv);
            #pragma unroll
            for (int rt = 0; rt < 4; ++rt) {
                f32x4 e = {0.f, 0.f, 0.f, 0.f};
                e = MFMA_BF16(aRes[rt][0], b0, e);
                e = MFMA_BF16(aRes[rt][1], b1, e);
                #pragma unroll
                for (int r = 0; r < 4; ++r)
                    sacc[rt][r] += EXP2(e[r]) * zinv;
            }
        }
        __syncthreads();
        #pragma unroll
        for (int rt = 0; rt < 4; ++rt) {
            #pragma unroll
            for (int r = 0; r < 4; ++r) {
                float v = sacc[rt][r];
                v += __shfl_xor(v, 1);
                v += __shfl_xor(v, 2);
                v += __shfl_xor(v, 4);
                v += __shfl_xor(v, 8);
                if (l15 == 0) reds[w * 64 + rt * 16 + lg * 4 + r] = v;
            }
        }
        __syncthreads();
        float facc = 0.f;
        #pragma unroll
        for (int q = 0; q < 8; ++q) {
            const int i = w * 8 + q;
            float si = 0.f;
            #pragma unroll
            for (int gg = 0; gg < 8; ++gg) si += reds[gg * 64 + i];
            const bf16* rowR = prb + (size_t)(i0 + i) * 64;
            const bf16* rowD = pdb + (size_t)(i0 + i) * 64;
            facc += si * (K_EINV * (float)rowR[lane] + (float)rowD[lane]);
        }
        __syncthreads();
        reds[w * 64 + lane] = facc;
        __syncthreads();
        if (tid < 64) {
            float s = 0.f;
            #pragma unroll
            for (int gg = 0; gg < 8; ++gg) s += reds[gg * 64 + tid];
            gapPart[((size_t)b * 64 + g) * 64 + tid] = s;
        }
    }
    __threadfence();
    grid.sync();

    // ================= P4: reduce partials -> red2[32][64] =================
    if (bid < 32) {
        float* red4 = (float*)smem;
        const int bk = bid >> 3, ck = bid & 7;
        float acc = 0.f;
        #pragma unroll
        for (int t = 0; t < 2; ++t)
            acc += rgbdPart[((size_t)bk * 128 + ck * 16 + w * 2 + t) * 64 + lane];
        acc += gapPart[((size_t)bk * 64 + ck * 8 + w) * 64 + lane];
        red4[w * 64 + lane] = acc;
        __syncthreads();
        if (tid < 64) {
            float s = 0.f;
            #pragma unroll
            for (int gg = 0; gg < 8; ++gg) s += red4[gg * 64 + tid];
            red2[bid * 64 + tid] = s;
        }
    }
    __threadfence();
    grid.sync();

    // ================= P5: gate (block 0) ==================================
    if (bid == 0) {
        float* gv = (float*)smem;            // [4][64]
        float* h  = (float*)(smem + 1024);   // [4][24]
        const int g4 = w & 3;
        float acc = 0.f;
        #pragma unroll
        for (int t = 0; t < 8; ++t) acc += red2[(g4 * 8 + t) * 64 + lane];
        if (w < 4) gv[g4 * 64 + lane] = acc * (1.f / 4096.f);
        __syncthreads();
        if (w < 4 && lane < 24) {
            float a = 0.f;
            #pragma unroll
            for (int cc = 0; cc < 64; ++cc) a += mlp1_w[lane * 64 + cc] * gv[g4 * 64 + cc];
            float sc = bn2_g[lane] * rsqrtf(bn2_v[lane] + 1e-5f);
            a = a * sc + bn2_b[lane] - bn2_m[lane] * sc;
            h[g4 * 24 + lane] = a > 0.f ? a : 0.f;
        }
        __syncthreads();
        if (w < 4) {
            float u = 0.f;
            #pragma unroll
            for (int o = 0; o < 24; ++o) u += mlp2_w[lane * 24 + o] * h[g4 * 24 + o];
            float sc = bn3_g[lane] * rsqrtf(bn3_v[lane] + 1e-5f);
            u = u * sc + bn3_b[lane] - bn3_m[lane] * sc;
            outp[g4 * 64 + lane] = 1.f / (1.f + __expf(-u));
        }
    }
}

// ===========================================================================
// Fallback path: proven R5 kernels (verbatim structure)
// ===========================================================================
__global__ __launch_bounds__(256) void k_prep(
    const float* __restrict__ conv_w, const float* __restrict__ rgb_w,
    const float* __restrict__ dep_w,
    bf16* __restrict__ wC, bf16* __restrict__ wR, bf16* __restrict__ wD)
{
    const int gid = blockIdx.x * 256 + threadIdx.x;
    bf16x8 v;
    if (gid < 2048) {
        const int t = gid >> 9, kk = (gid >> 6) & 7, lane = gid & 63;
        const float* src = conv_w + (size_t)(t * 16 + (lane & 15)) * 256
                                  + kk * 32 + (lane >> 4) * 8;
        #pragma unroll
        for (int j = 0; j < 8; ++j) v[j] = (bf16)src[j];
        *(bf16x8*)(wC + (size_t)gid * 8) = v;
    } else if (gid < 2560) {
        const int g = gid - 2048;
        const int t = g >> 7, kk = (g >> 6) & 1, lane = g & 63;
        const float* src = rgb_w + (size_t)(t * 16 + (lane & 15)) * 64
                                 + kk * 32 + (lane >> 4) * 8;
        #pragma unroll
        for (int j = 0; j < 8; ++j) v[j] = (bf16)src[j];
        *(bf16x8*)(wR + (size_t)g * 8) = v;
    } else {
        const int g = gid - 2560;
        const int t = g >> 7, kk = (g >> 6) & 1, lane = g & 63;
        const float* src = dep_w + (size_t)(t * 16 + (lane & 15)) * 64
                                 + kk * 32 + (lane >> 4) * 8;
        #pragma unroll
        for (int j = 0; j < 8; ++j) v[j] = (bf16)src[j];
        *(bf16x8*)(wD + (size_t)g * 8) = v;
    }
}

__global__ __launch_bounds__(512, 4) void k_front(
    const float* __restrict__ rgb, const float* __restrict__ dep,
    const bf16* __restrict__ wC, const bf16* __restrict__ wR,
    const bf16* __restrict__ wD,
    const float* __restrict__ bn1_g, const float* __restrict__ bn1_b,
    const float* __restrict__ bn1_m, const float* __restrict__ bn1_v,
    bf16* __restrict__ pr_e, bf16* __restrict__ pd,
    float* __restrict__ rgbdPart)
{
    const int bid = blockIdx.x;
    const int xcd = bid & 7;
    const int b    = xcd >> 1;
    const int tile = ((bid >> 3) << 1) | (xcd & 1);
    const int p0   = tile * 32;
    const int tid = threadIdx.x;
    const int w   = tid >> 6;
    const int lane = tid & 63;
    const int l15 = lane & 15;
    const int lg  = lane >> 4;
    const int ot4 = w & 3;
    const int ot  = ot4 * 16;
    const int ph  = w >> 2;

    __shared__ float s1[64], b1[64];
    __shared__ __align__(16) unsigned char ldsD[32 * 128];
    __shared__ __align__(16) unsigned char ldsR[32 * 128];
    __shared__ float red[8][64];

    if (tid < 64) {
        float sc = bn1_g[tid] * rsqrtf(bn1_v[tid] + 1e-5f);
        s1[tid] = sc;
        b1[tid] = bn1_b[tid] - bn1_m[tid] * sc;
    }
    __syncthreads();

    bf16x8 aW[8];
    #pragma unroll
    for (int kk = 0; kk < 8; ++kk)
        aW[kk] = *(const bf16x8*)(wC + ((size_t)(ot4 * 8 + kk) * 64 + lane) * 8);

    const float* depb = dep + (size_t)b * 256 * 4096;
    const int p = p0 + ph * 16 + l15;
    f32x4 acc = {0.f, 0.f, 0.f, 0.f};
    #pragma unroll
    for (int kk = 0; kk < 8; ++kk) {
        bf16x8 bF;
        const int c0 = kk * 32 + lg * 8;
        #pragma unroll
        for (int j = 0; j < 8; ++j) bF[j] = (bf16)depb[(size_t)(c0 + j) * 4096 + p];
        acc = MFMA_BF16(aW[kk], bF, acc);
    }
    {
        const int pl = ph * 16 + l15;
        const int o0 = ot + lg * 4;
        bf16x4 v4;
        #pragma unroll
        for (int r = 0; r < 4; ++r) {
            float x = acc[r] * s1[o0 + r] + b1[o0 + r];
            v4[r] = (bf16)(x > 0.f ? x : 0.f);
        }
        *(bf16x4*)(ldsD + swz128(pl, o0 * 2)) = v4;
    }
    const float* rgbb = rgb + (size_t)b * 64 * 4096;
    #pragma unroll
    for (int rep = 0; rep < 4; ++rep) {
        const int idx = rep * 512 + tid;
        const int c = idx >> 5, pp = idx & 31;
        *(bf16*)(ldsR + swz128(pp, c * 2)) = (bf16)rgbb[(size_t)c * 4096 + p0 + pp];
    }
    __syncthreads();

    bf16x8 aR[2], aD[2];
    #pragma unroll
    for (int kk = 0; kk < 2; ++kk) {
        aR[kk] = *(const bf16x8*)(wR + ((size_t)(ot4 * 2 + kk) * 64 + lane) * 8);
        aD[kk] = *(const bf16x8*)(wD + ((size_t)(ot4 * 2 + kk) * 64 + lane) * 8);
    }
    {
        f32x4 accR = {0.f, 0.f, 0.f, 0.f}, accD = {0.f, 0.f, 0.f, 0.f};
        const int pl = ph * 16 + l15;
        #pragma unroll
        for (int kk = 0; kk < 2; ++kk) {
            const int cb = (kk * 32 + lg * 8) * 2;
            bf16x8 bR = *(const bf16x8*)(ldsR + swz128(pl, cb));
            bf16x8 bD = *(const bf16x8*)(ldsD + swz128(pl, cb));
            accR = MFMA_BF16(aR[kk], bR, accR);
            accD = MFMA_BF16(aD[kk], bD, accD);
        }
        bf16x4 vR, vD;
        #pragma unroll
        for (int r = 0; r < 4; ++r) {
            vR[r] = (bf16)(accR[r] * K_E);
            vD[r] = (bf16)accD[r];
        }
        const size_t ob = ((size_t)b * 4096 + p0 + pl) * 64 + ot + lg * 4;
        *(bf16x4*)(pr_e + ob) = vR;
        *(bf16x4*)(pd + ob) = vD;
    }
    {
        const int c = tid & 63, g8 = tid >> 6;
        float sum = 0.f;
        #pragma unroll
        for (int q = 0; q < 4; ++q) {
            const int pp = g8 * 4 + q;
            sum += (float)*(const bf16*)(ldsR + swz128(pp, c * 2))
                 + (float)*(const bf16*)(ldsD + swz128(pp, c * 2));
        }
        red[g8][c] = sum;
    }
    __syncthreads();
    if (tid < 64) {
        float s = 0.f;
        #pragma unroll
        for (int g = 0; g < 8; ++g) s += red[g][tid];
        rgbdPart[((size_t)b * 128 + tile) * 64 + tid] = s;
    }
}

__global__ __launch_bounds__(256, 4) void k_zcol(
    const bf16* __restrict__ pr_e, const bf16* __restrict__ pd,
    float* __restrict__ Zpart)
{
    const int bid = blockIdx.x;
    const int xcd = bid & 7, b = xcd >> 1;
    const int sub = ((bid >> 3) << 1) | (xcd & 1);
    const int j0 = (sub & 63) * 64;
    const int ic = sub >> 6;
    const int tid = threadIdx.x, w = tid >> 6, lane = tid & 63;
    const int l15 = lane & 15, lg = lane >> 4;
    __shared__ float redz[4][64];

    const bf16* prb = pr_e + (size_t)b * 4096 * 64;
    const bf16* pdb = pd   + (size_t)b * 4096 * 64;
    const int cOff = lg * 8;

    bf16x8 bRes[4][2];
    #pragma unroll
    for (int jt = 0; jt < 4; ++jt) {
        const bf16* q = pdb + (size_t)(j0 + jt * 16 + l15) * 64 + cOff;
        bRes[jt][0] = *(const bf16x8*)q;
        bRes[jt][1] = *(const bf16x8*)(q + 32);
    }
    float zp[4] = {0.f, 0.f, 0.f, 0.f};
    const bf16* pa = prb + ((size_t)ic * 1024 + w * 16 + l15) * 64 + cOff;
    #pragma unroll 2
    for (int it = 0; it < 16; ++it) {
        bf16x8 a0 = *(const bf16x8*)pa;
        bf16x8 a1 = *(const bf16x8*)(pa + 32);
        pa += 64 * 64;
        #pragma unroll
        for (int jt = 0; jt < 4; ++jt) {
            f32x4 e = {0.f, 0.f, 0.f, 0.f};
            e = MFMA_BF16(a0, bRes[jt][0], e);
            e = MFMA_BF16(a1, bRes[jt][1], e);
            zp[jt] += (EXP2(e[0]) + EXP2(e[1])) + (EXP2(e[2]) + EXP2(e[3]));
        }
    }
    #pragma unroll
    for (int jt = 0; jt < 4; ++jt) {
        float v = zp[jt];
        v += __shfl_xor(v, 16);
        v += __shfl_xor(v, 32);
        if (lane < 16) redz[w][jt * 16 + lane] = v;
    }
    __syncthreads();
    if (tid < 64)
        Zpart[(((size_t)ic * 4 + b) << 12) + j0 + tid] =
            (redz[0][tid] + redz[1][tid]) + (redz[2][tid] + redz[3][tid]);
}

__global__ __launch_bounds__(256, 4) void k_srow(
    const bf16* __restrict__ pr_e, const bf16* __restrict__ pd,
    const float* __restrict__ Zpart, float* __restrict__ gapPart)
{
    const int bid = blockIdx.x;
    const int xcd = bid & 7, b = xcd >> 1;
    const int sub = ((bid >> 3) << 1) | (xcd & 1);
    const int i0 = (sub & 63) * 64;
    const int jc = sub >> 6;
    const int tid = threadIdx.x, w = tid >> 6, lane = tid & 63;
    const int l15 = lane & 15, lg = lane >> 4;
    __shared__ float reds[4][64];

    const bf16* prb = pr_e + (size_t)b * 4096 * 64;
    const bf16* pdb = pd   + (size_t)b * 4096 * 64;
    const int cOff = lg * 8;

    bf16x8 aRes[4][2];
    #pragma unroll
    for (int rt = 0; rt < 4; ++rt) {
        const bf16* q = prb + (size_t)(i0 + rt * 16 + l15) * 64 + cOff;
        aRes[rt][0] = *(const bf16x8*)q;
        aRes[rt][1] = *(const bf16x8*)(q + 32);
    }
    float sacc[4][4] = {};
    const bf16*  pb = pdb + ((size_t)jc * 1024 + w * 16 + l15) * 64 + cOff;
    const float* pz = Zpart + (b << 12) + jc * 1024 + w * 16 + l15;
    #pragma unroll 2
    for (int it = 0; it < 16; ++it) {
        bf16x8 b0 = *(const bf16x8*)pb;
        bf16x8 b1 = *(const bf16x8*)(pb + 32);
        pb += 64 * 64;
        float Zv = (pz[0] + pz[16384]) + (pz[32768] + pz[49152]);
        pz += 64;
        float zinv = __builtin_amdgcn_rcpf(Zv);
        zinv = zinv * (2.0f - Zv * zinv);
        #pragma unroll
        for (int rt = 0; rt < 4; ++rt) {
            f32x4 e = {0.f, 0.f, 0.f, 0.f};
            e = MFMA_BF16(aRes[rt][0], b0, e);
            e = MFMA_BF16(aRes[rt][1], b1, e);
            #pragma unroll
            for (int r = 0; r < 4; ++r)
                sacc[rt][r] += EXP2(e[r]) * zinv;
        }
    }
    #pragma unroll
    for (int rt = 0; rt < 4; ++rt) {
        #pragma unroll
        for (int r = 0; r < 4; ++r) {
            float v = sacc[rt][r];
            v += __shfl_xor(v, 1);
            v += __shfl_xor(v, 2);
            v += __shfl_xor(v, 4);
            v += __shfl_xor(v, 8);
            if (l15 == 0) reds[w][rt * 16 + lg * 4 + r] = v;
        }
    }
    __syncthreads();
    const int cg = tid >> 6, c = lane;
    float facc = 0.f;
    #pragma unroll
    for (int q = 0; q < 16; ++q) {
        const int i = cg * 16 + q;
        const float si = (reds[0][i] + reds[1][i]) + (reds[2][i] + reds[3][i]);
        const bf16* rowR = prb + (size_t)(i0 + i) * 64;
        const bf16* rowD = pdb + (size_t)(i0 + i) * 64;
        facc += si * (K_EINV * (float)rowR[c] + (float)rowD[c]);
    }
    __syncthreads();
    reds[cg][c] = facc;
    __syncthreads();
    if (tid < 64)
        gapPart[((size_t)b * 256 + sub) * 64 + tid] =
            (reds[0][tid] + reds[1][tid]) + (reds[2][tid] + reds[3][tid]);
}

__global__ __launch_bounds__(256) void k_gate(
    const float* __restrict__ gapPart, const float* __restrict__ rgbdPart,
    const float* __restrict__ mlp1_w,
    const float* __restrict__ bn2_g, const float* __restrict__ bn2_b,
    const float* __restrict__ bn2_m, const float* __restrict__ bn2_v,
    const float* __restrict__ mlp2_w,
    const float* __restrict__ bn3_g, const float* __restrict__ bn3_b,
    const float* __restrict__ bn3_m, const float* __restrict__ bn3_v,
    float* __restrict__ out)
{
    const int b = blockIdx.x, tid = threadIdx.x;
    const int c = tid & 63, g = tid >> 6;
    __shared__ float red[4][64];
    __shared__ float gv[64], h[24];

    float acc = 0.f;
    const float* rp = rgbdPart + ((size_t)b * 128 + g * 32) * 64 + c;
    #pragma unroll 4
    for (int t = 0; t < 32; ++t) acc += rp[t * 64];
    const float* gp = gapPart + ((size_t)b * 256 + g * 64) * 64 + c;
    #pragma unroll 4
    for (int t = 0; t < 64; ++t) acc += gp[t * 64];
    red[g][c] = acc;
    __syncthreads();
    if (tid < 64)
        gv[tid] = ((red[0][tid] + red[1][tid]) + (red[2][tid] + red[3][tid]))
                  * (1.f / 4096.f);
    __syncthreads();
    if (tid < 24) {
        float a = 0.f;
        #pragma unroll
        for (int cc = 0; cc < 64; ++cc) a += mlp1_w[tid * 64 + cc] * gv[cc];
        float sc = bn2_g[tid] * rsqrtf(bn2_v[tid] + 1e-5f);
        a = a * sc + bn2_b[tid] - bn2_m[tid] * sc;
        h[tid] = a > 0.f ? a : 0.f;
    }
    __syncthreads();
    if (tid < 64) {
        float u = 0.f;
        #pragma unroll
        for (int o = 0; o < 24; ++o) u += mlp2_w[tid * 24 + o] * h[o];
        float sc = bn3_g[tid] * rsqrtf(bn3_v[tid] + 1e-5f);
        u = u * sc + bn3_b[tid] - bn3_m[tid] * sc;
        out[b * 64 + tid] = 1.f / (1.f + __expf(-u));
    }
}

// ---------------------------------------------------------------------------
extern "C" void kernel_launch(void* const* d_in, const int* in_sizes, int n_in,
                              void* d_out, int out_size, void* d_ws, size_t ws_size,
                              hipStream_t stream)
{
    const float* rgb    = (const float*)d_in[0];
    const float* dep    = (const float*)d_in[1];
    const float* conv_w = (const float*)d_in[2];
    const float* bn1_g  = (const float*)d_in[3];
    const float* bn1_b  = (const float*)d_in[4];
    const float* bn1_m  = (const float*)d_in[5];
    const float* bn1_v  = (const float*)d_in[6];
    const float* rgb_w  = (const float*)d_in[7];
    const float* dep_w  = (const float*)d_in[8];
    const float* mlp1_w = (const float*)d_in[9];
    const float* bn2_g  = (const float*)d_in[10];
    const float* bn2_b  = (const float*)d_in[11];
    const float* bn2_m  = (const float*)d_in[12];
    const float* bn2_v  = (const float*)d_in[13];
    const float* mlp2_w = (const float*)d_in[14];
    const float* bn3_g  = (const float*)d_in[15];
    const float* bn3_b  = (const float*)d_in[16];
    const float* bn3_m  = (const float*)d_in[17];
    const float* bn3_v  = (const float*)d_in[18];

    char* ws = (char*)d_ws;
    bf16*  pr_e     = (bf16*)(ws);                                  // 2 MB
    bf16*  pdBuf    = (bf16*)(ws + (2u << 20));                     // 2 MB
    float* Zbuf     = (float*)(ws + (4u << 20));                    // 64 KB (coop)
    float* ZpartFB  = (float*)(ws + (4u << 20) + (64u << 10));      // 256 KB (fb)
    float* rgbdPart = (float*)(ws + (4u << 20) + (320u << 10));     // 128 KB
    float* gapPart  = (float*)(ws + (4u << 20) + (448u << 10));     // 256 KB
    float* red2     = (float*)(ws + (4u << 20) + (704u << 10));     // 8 KB
    bf16*  wC       = (bf16*)(ws + (4u << 20) + (712u << 10));      // 32 KB
    bf16*  wR       = (bf16*)(ws + (4u << 20) + (744u << 10));      // 8 KB
    bf16*  wD       = (bf16*)(ws + (4u << 20) + (752u << 10));      // 8 KB
    float* outp     = (float*)d_out;

    void* args[] = {
        (void*)&rgb, (void*)&dep, (void*)&conv_w,
        (void*)&bn1_g, (void*)&bn1_b, (void*)&bn1_m, (void*)&bn1_v,
        (void*)&rgb_w, (void*)&dep_w,
        (void*)&mlp1_w, (void*)&bn2_g, (void*)&bn2_b, (void*)&bn2_m, (void*)&bn2_v,
        (void*)&mlp2_w, (void*)&bn3_g, (void*)&bn3_b, (void*)&bn3_m, (void*)&bn3_v,
        (void*)&wC, (void*)&wR, (void*)&wD, (void*)&pr_e, (void*)&pdBuf,
        (void*)&Zbuf, (void*)&rgbdPart, (void*)&gapPart, (void*)&red2,
        (void*)&outp
    };
    hipError_t rc = hipLaunchCooperativeKernel((const void*)k_fused, dim3(256),
                                               dim3(512), args, 0, stream);
    if (rc != hipSuccess) {
        // Fallback: proven 5-kernel pipeline (R5)
        k_prep<<<12, 256, 0, stream>>>(conv_w, rgb_w, dep_w, wC, wR, wD);
        k_front<<<512, 512, 0, stream>>>(rgb, dep, wC, wR, wD,
                                         bn1_g, bn1_b, bn1_m, bn1_v,
                                         pr_e, pdBuf, rgbdPart);
        k_zcol<<<1024, 256, 0, stream>>>(pr_e, pdBuf, ZpartFB);
        k_srow<<<1024, 256, 0, stream>>>(pr_e, pdBuf, ZpartFB, gapPart);
        k_gate<<<4, 256, 0, stream>>>(gapPart, rgbdPart, mlp1_w,
                                      bn2_g, bn2_b, bn2_m, bn2_v, mlp2_w,
                                      bn3_g, bn3_b, bn3_m, bn3_v, outp);
    }
}

// Round 8
// 114.457 us; speedup vs baseline: 3.3335x; 3.3335x over previous
//
#include <hip/hip_runtime.h>
#include <hip/hip_bf16.h>

// ---------------------------------------------------------------------------
// R8: single-pass attention stats.
//   gap_att[c] = sum_j W[j,c]/Z[j],  W[j,c] = sum_i p_ij * v[i,c],
//   Z[j] = sum_i p_ij,  p_ij = exp2(e2_ij),  v = pr+pd.
// One traversal of e (was two), 67M exps (was 134M), k_srow eliminated.
// W-GEMM uses mfma 16x16x16 bf16: e-MFMA D-layout == K=16 A-frag layout for
// A=P^T (lane holds p[j=l15][i=lg*4+r]) -> no shuffles.
// Pipeline: k_prep -> k_front(+pv) -> k_colpass -> k_gate.  No coop (R7:
// grid.sync ~60us each, 377us total — abandoned).
// ---------------------------------------------------------------------------

typedef __bf16 bf16;
typedef __bf16 bf16x4 __attribute__((ext_vector_type(4)));
typedef __bf16 bf16x8 __attribute__((ext_vector_type(8)));
typedef float  f32x4  __attribute__((ext_vector_type(4)));
typedef short  s4     __attribute__((ext_vector_type(4)));

#define MFMA_BF16(a, b, c) __builtin_amdgcn_mfma_f32_16x16x32_bf16((a), (b), (c), 0, 0, 0)

#if defined(__has_builtin)
# if __has_builtin(__builtin_amdgcn_mfma_f32_16x16x16bf16_1k)
#  define MFMA16_BUILTIN(a, b, c) __builtin_amdgcn_mfma_f32_16x16x16bf16_1k((a), (b), (c), 0, 0, 0)
# elif __has_builtin(__builtin_amdgcn_mfma_f32_16x16x16_bf16)
#  define MFMA16_BUILTIN(a, b, c) __builtin_amdgcn_mfma_f32_16x16x16_bf16((a), (b), (c), 0, 0, 0)
# endif
#endif

__device__ __forceinline__ f32x4 MFMA16(s4 a, s4 b, f32x4 c) {
#ifdef MFMA16_BUILTIN
    return MFMA16_BUILTIN(a, b, c);
#else
    asm("v_mfma_f32_16x16x16_bf16 %0, %1, %2, %0" : "+v"(c) : "v"(a), "v"(b));
    return c;
#endif
}

#if defined(__has_builtin)
# if __has_builtin(__builtin_amdgcn_exp2f)
#  define EXP2(x) __builtin_amdgcn_exp2f(x)
# else
#  define EXP2(x) exp2f(x)
# endif
#else
# define EXP2(x) exp2f(x)
#endif

#define K_E 0.18033688f      // 0.125 * log2(e)

__device__ __forceinline__ int swz128(int row, int colByte) {
    return row * 128 + (colByte ^ ((row & 7) << 4));
}

// ---------------------------------------------------------------------------
// K0: pack weights into fragment-ordered bf16 (one 16B/lane load per frag).
// ---------------------------------------------------------------------------
__global__ __launch_bounds__(256) void k_prep(
    const float* __restrict__ conv_w, const float* __restrict__ rgb_w,
    const float* __restrict__ dep_w,
    bf16* __restrict__ wC, bf16* __restrict__ wR, bf16* __restrict__ wD)
{
    const int gid = blockIdx.x * 256 + threadIdx.x;
    bf16x8 v;
    if (gid < 2048) {
        const int t = gid >> 9, kk = (gid >> 6) & 7, lane = gid & 63;
        const float* src = conv_w + (size_t)(t * 16 + (lane & 15)) * 256
                                  + kk * 32 + (lane >> 4) * 8;
        #pragma unroll
        for (int j = 0; j < 8; ++j) v[j] = (bf16)src[j];
        *(bf16x8*)(wC + (size_t)gid * 8) = v;
    } else if (gid < 2560) {
        const int g = gid - 2048;
        const int t = g >> 7, kk = (g >> 6) & 1, lane = g & 63;
        const float* src = rgb_w + (size_t)(t * 16 + (lane & 15)) * 64
                                 + kk * 32 + (lane >> 4) * 8;
        #pragma unroll
        for (int j = 0; j < 8; ++j) v[j] = (bf16)src[j];
        *(bf16x8*)(wR + (size_t)g * 8) = v;
    } else {
        const int g = gid - 2560;
        const int t = g >> 7, kk = (g >> 6) & 1, lane = g & 63;
        const float* src = dep_w + (size_t)(t * 16 + (lane & 15)) * 64
                                 + kk * 32 + (lane >> 4) * 8;
        #pragma unroll
        for (int j = 0; j < 8; ++j) v[j] = (bf16)src[j];
        *(bf16x8*)(wD + (size_t)g * 8) = v;
    }
}

// ---------------------------------------------------------------------------
// K1: conv+BN+ReLU -> proj: pr_e (exp2-scaled), pd, pv=pr+pd; rgbd partials.
// 512 blocks XCD-affine x 512 thr.
// ---------------------------------------------------------------------------
__global__ __launch_bounds__(512, 4) void k_front(
    const float* __restrict__ rgb, const float* __restrict__ dep,
    const bf16* __restrict__ wC, const bf16* __restrict__ wR,
    const bf16* __restrict__ wD,
    const float* __restrict__ bn1_g, const float* __restrict__ bn1_b,
    const float* __restrict__ bn1_m, const float* __restrict__ bn1_v,
    bf16* __restrict__ pr_e, bf16* __restrict__ pd, bf16* __restrict__ pv,
    float* __restrict__ rgbdPart)
{
    const int bid = blockIdx.x;
    const int xcd = bid & 7;
    const int b    = xcd >> 1;
    const int tile = ((bid >> 3) << 1) | (xcd & 1);
    const int p0   = tile * 32;
    const int tid = threadIdx.x;
    const int w   = tid >> 6;
    const int lane = tid & 63;
    const int l15 = lane & 15;
    const int lg  = lane >> 4;
    const int ot4 = w & 3;
    const int ot  = ot4 * 16;
    const int ph  = w >> 2;

    __shared__ float s1[64], b1[64];
    __shared__ __align__(16) unsigned char ldsD[32 * 128];
    __shared__ __align__(16) unsigned char ldsR[32 * 128];
    __shared__ float red[8][64];

    if (tid < 64) {
        float sc = bn1_g[tid] * rsqrtf(bn1_v[tid] + 1e-5f);
        s1[tid] = sc;
        b1[tid] = bn1_b[tid] - bn1_m[tid] * sc;
    }
    __syncthreads();

    bf16x8 aW[8];
    #pragma unroll
    for (int kk = 0; kk < 8; ++kk)
        aW[kk] = *(const bf16x8*)(wC + ((size_t)(ot4 * 8 + kk) * 64 + lane) * 8);

    const float* depb = dep + (size_t)b * 256 * 4096;
    const int p = p0 + ph * 16 + l15;
    f32x4 acc = {0.f, 0.f, 0.f, 0.f};
    #pragma unroll
    for (int kk = 0; kk < 8; ++kk) {
        bf16x8 bF;
        const int c0 = kk * 32 + lg * 8;
        #pragma unroll
        for (int j = 0; j < 8; ++j) bF[j] = (bf16)depb[(size_t)(c0 + j) * 4096 + p];
        acc = MFMA_BF16(aW[kk], bF, acc);
    }
    {
        const int pl = ph * 16 + l15;
        const int o0 = ot + lg * 4;
        bf16x4 v4;
        #pragma unroll
        for (int r = 0; r < 4; ++r) {
            float x = acc[r] * s1[o0 + r] + b1[o0 + r];
            v4[r] = (bf16)(x > 0.f ? x : 0.f);
        }
        *(bf16x4*)(ldsD + swz128(pl, o0 * 2)) = v4;
    }
    const float* rgbb = rgb + (size_t)b * 64 * 4096;
    #pragma unroll
    for (int rep = 0; rep < 4; ++rep) {
        const int idx = rep * 512 + tid;
        const int c = idx >> 5, pp = idx & 31;
        *(bf16*)(ldsR + swz128(pp, c * 2)) = (bf16)rgbb[(size_t)c * 4096 + p0 + pp];
    }
    __syncthreads();

    bf16x8 aR[2], aD[2];
    #pragma unroll
    for (int kk = 0; kk < 2; ++kk) {
        aR[kk] = *(const bf16x8*)(wR + ((size_t)(ot4 * 2 + kk) * 64 + lane) * 8);
        aD[kk] = *(const bf16x8*)(wD + ((size_t)(ot4 * 2 + kk) * 64 + lane) * 8);
    }
    {
        f32x4 accR = {0.f, 0.f, 0.f, 0.f}, accD = {0.f, 0.f, 0.f, 0.f};
        const int pl = ph * 16 + l15;
        #pragma unroll
        for (int kk = 0; kk < 2; ++kk) {
            const int cb = (kk * 32 + lg * 8) * 2;
            bf16x8 bR = *(const bf16x8*)(ldsR + swz128(pl, cb));
            bf16x8 bD = *(const bf16x8*)(ldsD + swz128(pl, cb));
            accR = MFMA_BF16(aR[kk], bR, accR);
            accD = MFMA_BF16(aD[kk], bD, accD);
        }
        bf16x4 vR, vD, vP;
        #pragma unroll
        for (int r = 0; r < 4; ++r) {
            vR[r] = (bf16)(accR[r] * K_E);
            vD[r] = (bf16)accD[r];
            vP[r] = (bf16)(accR[r] + accD[r]);
        }
        const size_t ob = ((size_t)b * 4096 + p0 + pl) * 64 + ot + lg * 4;
        *(bf16x4*)(pr_e + ob) = vR;
        *(bf16x4*)(pd + ob) = vD;
        *(bf16x4*)(pv + ob) = vP;
    }
    {
        const int c = tid & 63, g8 = tid >> 6;
        float sum = 0.f;
        #pragma unroll
        for (int q = 0; q < 4; ++q) {
            const int pp = g8 * 4 + q;
            sum += (float)*(const bf16*)(ldsR + swz128(pp, c * 2))
                 + (float)*(const bf16*)(ldsD + swz128(pp, c * 2));
        }
        red[g8][c] = sum;
    }
    __syncthreads();
    if (tid < 64) {
        float s = 0.f;
        #pragma unroll
        for (int g = 0; g < 8; ++g) s += red[g][tid];
        rgbdPart[((size_t)b * 128 + tile) * 64 + tid] = s;
    }
}

// ---------------------------------------------------------------------------
// K2: single-pass column stats. 256 blocks (4b x 64 j-tiles, XCD-affine)
// x 1024 thr (16 waves: ih=w>>2 streams i-tiles 4q+ih, jt=w&3 owns 16 j).
// Per iter: e = pr_e x pd (MFMA K=64), p = exp2(e), Z += p,
//           W[j,c] += P^T x pv (4x MFMA 16x16x16, A-frag = p in-place).
// Epilogue: LDS reduce over ih, gapPart[b][jt64][c] = sum_j W[j,c]/Z[j].
// ---------------------------------------------------------------------------
__global__ __launch_bounds__(1024, 4) void k_colpass(
    const bf16* __restrict__ pr_e, const bf16* __restrict__ pd,
    const bf16* __restrict__ pv, float* __restrict__ gapPart)
{
    const int bid = blockIdx.x;
    const int xcd = bid & 7, b = xcd >> 1;
    const int jt64 = ((bid >> 3) << 1) | (xcd & 1);   // 0..63
    const int j0 = jt64 * 64;
    const int tid = threadIdx.x;
    const int w = tid >> 6, lane = tid & 63;
    const int l15 = lane & 15, lg = lane >> 4;
    const int ih = w >> 2, jt = w & 3;

    // LDS: w_lds[4][64][64] f32 (64KB) | g_lds[64][64] f32 (16KB) | z_lds[4][64]
    __shared__ __align__(16) float w_lds[4][64][64];
    __shared__ __align__(16) float g_lds[64][64];
    __shared__ float z_lds[4][64];

    const bf16* prb = pr_e + (size_t)b * 4096 * 64;
    const bf16* pdb = pd   + (size_t)b * 4096 * 64;
    const bf16* pvb = pv   + (size_t)b * 4096 * 64;
    const int cOff = lg * 8;

    // resident B (pd) for this wave's 16 j
    bf16x8 b0, b1;
    {
        const bf16* q = pdb + (size_t)(j0 + jt * 16 + l15) * 64 + cOff;
        b0 = *(const bf16x8*)q;
        b1 = *(const bf16x8*)(q + 32);
    }

    f32x4 accW[4] = {{0,0,0,0},{0,0,0,0},{0,0,0,0},{0,0,0,0}};
    float z = 0.f;

    for (int q = 0; q < 64; ++q) {
        const int itile = (q * 4 + ih) * 16;
        // e-GEMM A-frags (pr_e rows)
        const bf16* pa = prb + (size_t)(itile + l15) * 64 + cOff;
        bf16x8 a0 = *(const bf16x8*)pa;
        bf16x8 a1 = *(const bf16x8*)(pa + 32);
        f32x4 e = {0.f, 0.f, 0.f, 0.f};
        e = MFMA_BF16(a0, b0, e);
        e = MFMA_BF16(a1, b1, e);
        // p = exp2(e); Z accum; pack to bf16 A-frag (layout matches K=16 A)
        bf16x4 ph;
        #pragma unroll
        for (int r = 0; r < 4; ++r) {
            float pf = EXP2(e[r]);
            z += pf;
            ph[r] = (bf16)pf;
        }
        const s4 paF = __builtin_bit_cast(s4, ph);
        // W-GEMM: B-frag = pv[itile+lg*4+jj][cb*16+l15]
        const bf16* vrow = pvb + (size_t)(itile + lg * 4) * 64 + l15;
        #pragma unroll
        for (int cb = 0; cb < 4; ++cb) {
            bf16x4 vb;
            #pragma unroll
            for (int jj = 0; jj < 4; ++jj) vb[jj] = vrow[jj * 64 + cb * 16];
            accW[cb] = MFMA16(paF, __builtin_bit_cast(s4, vb), accW[cb]);
        }
    }

    // Z: reduce over lg groups within wave
    z += __shfl_xor(z, 16);
    z += __shfl_xor(z, 32);
    if (lane < 16) z_lds[ih][jt * 16 + lane] = z;
    // W: D layout col=l15 (c), row=lg*4+r (j within 16)
    #pragma unroll
    for (int cb = 0; cb < 4; ++cb) {
        #pragma unroll
        for (int r = 0; r < 4; ++r)
            w_lds[ih][jt * 16 + lg * 4 + r][cb * 16 + l15] = accW[cb][r];
    }
    __syncthreads();

    // assemble: thread t -> j = t>>4, c0 = (t&15)*4
    {
        const int j = tid >> 4, c0 = (tid & 15) * 4;
        float zj = (z_lds[0][j] + z_lds[1][j]) + (z_lds[2][j] + z_lds[3][j]);
        float zinv = __builtin_amdgcn_rcpf(zj);
        zinv = zinv * (2.0f - zj * zinv);
        f32x4 ws = *(const f32x4*)&w_lds[0][j][c0];
        #pragma unroll
        for (int ihh = 1; ihh < 4; ++ihh)
            ws += *(const f32x4*)&w_lds[ihh][j][c0];
        f32x4 g = ws * zinv;
        *(f32x4*)&g_lds[j][c0] = g;
    }
    __syncthreads();
    if (tid < 64) {
        float s = 0.f;
        #pragma unroll 8
        for (int j = 0; j < 64; ++j) s += g_lds[j][tid];
        gapPart[((size_t)b * 64 + jt64) * 64 + tid] = s;
    }
}

// ---------------------------------------------------------------------------
// K3: gap assembly -> mlp1+BN+ReLU -> mlp2+BN -> sigmoid (f32 out).
// ---------------------------------------------------------------------------
__global__ __launch_bounds__(256) void k_gate(
    const float* __restrict__ gapPart, const float* __restrict__ rgbdPart,
    const float* __restrict__ mlp1_w,
    const float* __restrict__ bn2_g, const float* __restrict__ bn2_b,
    const float* __restrict__ bn2_m, const float* __restrict__ bn2_v,
    const float* __restrict__ mlp2_w,
    const float* __restrict__ bn3_g, const float* __restrict__ bn3_b,
    const float* __restrict__ bn3_m, const float* __restrict__ bn3_v,
    float* __restrict__ out)
{
    const int b = blockIdx.x, tid = threadIdx.x;
    const int c = tid & 63, g = tid >> 6;
    __shared__ float red[4][64];
    __shared__ float gv[64], h[24];

    float acc = 0.f;
    const float* rp = rgbdPart + ((size_t)b * 128 + g * 32) * 64 + c;
    #pragma unroll 4
    for (int t = 0; t < 32; ++t) acc += rp[t * 64];
    const float* gp = gapPart + ((size_t)b * 64 + g * 16) * 64 + c;
    #pragma unroll 4
    for (int t = 0; t < 16; ++t) acc += gp[t * 64];
    red[g][c] = acc;
    __syncthreads();
    if (tid < 64)
        gv[tid] = ((red[0][tid] + red[1][tid]) + (red[2][tid] + red[3][tid]))
                  * (1.f / 4096.f);
    __syncthreads();
    if (tid < 24) {
        float a = 0.f;
        #pragma unroll
        for (int cc = 0; cc < 64; ++cc) a += mlp1_w[tid * 64 + cc] * gv[cc];
        float sc = bn2_g[tid] * rsqrtf(bn2_v[tid] + 1e-5f);
        a = a * sc + bn2_b[tid] - bn2_m[tid] * sc;
        h[tid] = a > 0.f ? a : 0.f;
    }
    __syncthreads();
    if (tid < 64) {
        float u = 0.f;
        #pragma unroll
        for (int o = 0; o < 24; ++o) u += mlp2_w[tid * 24 + o] * h[o];
        float sc = bn3_g[tid] * rsqrtf(bn3_v[tid] + 1e-5f);
        u = u * sc + bn3_b[tid] - bn3_m[tid] * sc;
        out[b * 64 + tid] = 1.f / (1.f + __expf(-u));
    }
}

// ---------------------------------------------------------------------------
extern "C" void kernel_launch(void* const* d_in, const int* in_sizes, int n_in,
                              void* d_out, int out_size, void* d_ws, size_t ws_size,
                              hipStream_t stream)
{
    const float* rgb    = (const float*)d_in[0];
    const float* dep    = (const float*)d_in[1];
    const float* conv_w = (const float*)d_in[2];
    const float* bn1_g  = (const float*)d_in[3];
    const float* bn1_b  = (const float*)d_in[4];
    const float* bn1_m  = (const float*)d_in[5];
    const float* bn1_v  = (const float*)d_in[6];
    const float* rgb_w  = (const float*)d_in[7];
    const float* dep_w  = (const float*)d_in[8];
    const float* mlp1_w = (const float*)d_in[9];
    const float* bn2_g  = (const float*)d_in[10];
    const float* bn2_b  = (const float*)d_in[11];
    const float* bn2_m  = (const float*)d_in[12];
    const float* bn2_v  = (const float*)d_in[13];
    const float* mlp2_w = (const float*)d_in[14];
    const float* bn3_g  = (const float*)d_in[15];
    const float* bn3_b  = (const float*)d_in[16];
    const float* bn3_m  = (const float*)d_in[17];
    const float* bn3_v  = (const float*)d_in[18];

    char* ws = (char*)d_ws;
    bf16*  pr_e     = (bf16*)(ws);                                  // 2 MB
    bf16*  pdBuf    = (bf16*)(ws + (2u << 20));                     // 2 MB
    bf16*  pvBuf    = (bf16*)(ws + (4u << 20));                     // 2 MB
    float* rgbdPart = (float*)(ws + (6u << 20));                    // 128 KB
    float* gapPart  = (float*)(ws + (6u << 20) + (128u << 10));     // 64 KB
    bf16*  wC       = (bf16*)(ws + (6u << 20) + (192u << 10));      // 32 KB
    bf16*  wR       = (bf16*)(ws + (6u << 20) + (224u << 10));      // 8 KB
    bf16*  wD       = (bf16*)(ws + (6u << 20) + (232u << 10));      // 8 KB

    k_prep<<<12, 256, 0, stream>>>(conv_w, rgb_w, dep_w, wC, wR, wD);
    k_front<<<512, 512, 0, stream>>>(rgb, dep, wC, wR, wD,
                                     bn1_g, bn1_b, bn1_m, bn1_v,
                                     pr_e, pdBuf, pvBuf, rgbdPart);
    k_colpass<<<256, 1024, 0, stream>>>(pr_e, pdBuf, pvBuf, gapPart);
    k_gate<<<4, 256, 0, stream>>>(gapPart, rgbdPart, mlp1_w,
                                  bn2_g, bn2_b, bn2_m, bn2_v, mlp2_w,
                                  bn3_g, bn3_b, bn3_m, bn3_v, (float*)d_out);
}